// Round 6
// baseline (820.742 us; speedup 1.0000x reference)
//
#include <hip/hip_runtime.h>
#include <hip/hip_bf16.h>
#include <stdint.h>

#define BATCH 8192
#define NNODE 20
#define MROWS 163840
#define KCONV 768
#define NCONV 768
#define QSCALE 0.17677669529663687f

typedef __bf16 bf16x8 __attribute__((ext_vector_type(8)));
typedef float f32x4 __attribute__((ext_vector_type(4)));
typedef unsigned short u16x8 __attribute__((ext_vector_type(8)));

#define GLOBAL_AS __attribute__((address_space(1)))
#define LDS_AS __attribute__((address_space(3)))

__device__ __forceinline__ void load_lds16(const void* g, void* l) {
  __builtin_amdgcn_global_load_lds((const GLOBAL_AS uint32_t*)g,
                                   (LDS_AS uint32_t*)l, 16, 0, 0);
}

__device__ __forceinline__ float bf2f(unsigned short u) {
  union { unsigned int i; float f; } x;
  x.i = ((unsigned int)u) << 16;
  return x.f;
}

// ---------------------------------------------------------------------------
// K1: prep — cast x to bf16, build WcT, cast wo, zero boundary row.
// ---------------------------------------------------------------------------
__global__ void prep_kernel(const float* __restrict__ x,
                            const float* __restrict__ wq,
                            const float* __restrict__ wk,
                            const float* __restrict__ wv,
                            const float* __restrict__ wo,
                            __hip_bfloat16* __restrict__ xb,
                            __hip_bfloat16* __restrict__ WcT,
                            __hip_bfloat16* __restrict__ wob,
                            int* __restrict__ zrow) {
  const int stride = gridDim.x * blockDim.x;
  const int gid = blockIdx.x * blockDim.x + threadIdx.x;

  if (gid < 128) zrow[gid] = 0;

  const int n8 = (MROWS * 256) / 8;
  for (int i8 = gid; i8 < n8; i8 += stride) {
    const float4* xp = ((const float4*)x) + (size_t)i8 * 2;
    float4 a = xp[0];
    float4 b = xp[1];
    __align__(16) __hip_bfloat16 h[8];
    h[0] = __float2bfloat16(a.x); h[1] = __float2bfloat16(a.y);
    h[2] = __float2bfloat16(a.z); h[3] = __float2bfloat16(a.w);
    h[4] = __float2bfloat16(b.x); h[5] = __float2bfloat16(b.y);
    h[6] = __float2bfloat16(b.z); h[7] = __float2bfloat16(b.w);
    ((int4*)xb)[i8] = *(const int4*)h;
  }

  for (int idx = gid; idx < NCONV * KCONV; idx += stride) {
    int n = idx / KCONV;
    int j = idx - n * KCONV;
    int c = n >> 8, o = n & 255;
    int t = j >> 8, i = j & 255;
    const float* w = (c == 0) ? wq : (c == 1) ? wk : wv;
    WcT[idx] = __float2bfloat16(w[(o * 256 + i) * 3 + t]);
  }

  for (int idx = gid; idx < 256 * 256; idx += stride) {
    wob[idx] = __float2bfloat16(wo[idx]);
  }
}

// ---------------------------------------------------------------------------
// K2: conv GEMM, m97 recipe + XCD-aware swizzle (T1): 1-D grid of 7680,
// xcd = bid&7 (round-robin dispatch), each XCD owns a contiguous band of
// 160 m-tiles and iterates the 6 n-tiles of each m-panel locally, so the
// A panel is fetched into exactly one XCD L2 (was ~6x HBM re-fetch).
// Bijective: 7680 = 8 * 160 * 6 exactly.
// ---------------------------------------------------------------------------
__global__ __launch_bounds__(256) void conv_gemm_kernel(
    const __hip_bfloat16* __restrict__ xb,
    const __hip_bfloat16* __restrict__ WcT,
    __hip_bfloat16* __restrict__ y,
    const __hip_bfloat16* __restrict__ zrow) {
  __shared__ __align__(16) __hip_bfloat16 As[128 * 64];
  __shared__ __align__(16) __hip_bfloat16 Bs[128 * 64];

  const int tid = threadIdx.x;
  const int lane = tid & 63;
  const int wave = tid >> 6;
  const int wm = (wave >> 1) << 6;
  const int wn = (wave & 1) << 6;
  const int l16 = lane & 15;
  const int quad = lane >> 4;

  const int bid = blockIdx.x;
  const int xcd = bid & 7;
  const int q = bid >> 3;          // 0..959
  const int qm = q / 6;            // 0..159
  const int nt = q - qm * 6;       // 0..5
  const int m0 = (xcd * 160 + qm) * 128;
  const int n0 = nt * 128;

  const __hip_bfloat16* a_base[4];
  const __hip_bfloat16* z_base[4];
  const __hip_bfloat16* b_base[4];
  int a_node[4];
  int lds_off[4];
#pragma unroll
  for (int it = 0; it < 4; ++it) {
    int flat = ((it * 4 + wave) << 6) + lane;
    int row = flat >> 3;
    int seg = flat & 7;
    int seg_g = seg ^ (row & 7);
    int gr = m0 + row;
    int b = gr / 20;
    int node = gr - b * 20;
    a_node[it] = node;
    a_base[it] = xb + (long)(gr - 1) * 256 + seg_g * 8;
    z_base[it] = zrow + seg_g * 8;
    b_base[it] = WcT + (size_t)(n0 + row) * KCONV + seg_g * 8;
    lds_off[it] = (it * 4 + wave) << 9;
  }

  f32x4 acc[4][4];
  const f32x4 zero = {0.f, 0.f, 0.f, 0.f};
#pragma unroll
  for (int i = 0; i < 4; ++i)
#pragma unroll
    for (int j = 0; j < 4; ++j) acc[i][j] = zero;

  for (int kt = 0; kt < 12; ++kt) {
    const int t = kt >> 2;
    const int i0 = (kt & 3) << 6;
    const int k0 = kt << 6;
#pragma unroll
    for (int it = 0; it < 4; ++it) {
      bool ok = (unsigned)(a_node[it] + t - 1) < 20u;
      const __hip_bfloat16* ga = ok ? (a_base[it] + t * 256 + i0) : z_base[it];
      load_lds16(ga, &As[lds_off[it]]);
      load_lds16(b_base[it] + k0, &Bs[lds_off[it]]);
    }
    __syncthreads();

#pragma unroll
    for (int kk = 0; kk < 64; kk += 32) {
      const int sx = (((kk >> 3) + quad) ^ (l16 & 7)) << 3;
      bf16x8 af[4], bfr[4];
#pragma unroll
      for (int i = 0; i < 4; ++i)
        af[i] = *(const bf16x8*)&As[((wm + i * 16 + l16) << 6) + sx];
#pragma unroll
      for (int j = 0; j < 4; ++j)
        bfr[j] = *(const bf16x8*)&Bs[((wn + j * 16 + l16) << 6) + sx];
#pragma unroll
      for (int i = 0; i < 4; ++i)
#pragma unroll
        for (int j = 0; j < 4; ++j)
          acc[i][j] = __builtin_amdgcn_mfma_f32_16x16x32_bf16(af[i], bfr[j],
                                                              acc[i][j], 0, 0, 0);
    }
    __syncthreads();
  }

#pragma unroll
  for (int i = 0; i < 4; ++i)
#pragma unroll
    for (int j = 0; j < 4; ++j)
#pragma unroll
      for (int r = 0; r < 4; ++r) {
        int row = m0 + wm + i * 16 + quad * 4 + r;
        int col = n0 + wn + j * 16 + l16;
        y[(size_t)row * NCONV + col] = __float2bfloat16(acc[i][j][r]);
      }
}

// ---------------------------------------------------------------------------
// K3: attention, wave-local edition (unchanged from round 5's win).
// ---------------------------------------------------------------------------
#define YST 776
__global__ __launch_bounds__(256) void attn5_kernel(
    const __hip_bfloat16* __restrict__ y,
    const __hip_bfloat16* __restrict__ xb,
    const float* __restrict__ rel,
    const float* __restrict__ gbias,
    const float* __restrict__ alpha_p,
    const float* __restrict__ gq, const float* __restrict__ bq,
    const float* __restrict__ gk, const float* __restrict__ bk,
    const float* __restrict__ gv, const float* __restrict__ bv,
    __hip_bfloat16* __restrict__ ao) {
  __shared__ __align__(16) __hip_bfloat16 yS[20 * YST];  // 31040 B only

  const int b = blockIdx.x;
  const int tid = threadIdx.x;
  const float alpha = alpha_p[0];
  const int lane = tid & 63;
  const int wave = tid >> 6;
  const int l16 = lane & 15;
  const int quad = lane >> 4;
  const f32x4 zero = {0.f, 0.f, 0.f, 0.f};

  // ---- phase 1: stage yS + prefetch xb residual ----
  const int4* src4 = (const int4*)(y + (size_t)b * NNODE * 768);
#pragma unroll
  for (int p = 0; p < 8; ++p) {
    int idx = tid + p * 256;
    if (idx < 1920) {
      int r = idx / 96;
      int c = idx - r * 96;
      *(int4*)&yS[r * YST + c * 8] = src4[idx];
    }
  }
  u16x8 xr[8];
  if (tid < 240) {
    const int rc = tid >> 2;
    const int p = tid & 3;
    const int r = rc / 3;
    const unsigned short* xp =
        (const unsigned short*)&xb[(((size_t)b * NNODE + r)) << 8];
#pragma unroll
    for (int s = 0; s < 8; ++s) xr[s] = *(const u16x8*)&xp[(s * 4 + p) * 8];
  }
  __syncthreads();

  // ---- phase 2: LN + residual in LDS; Q chunk pre-scaled by 1/sqrt(dk) ----
  if (tid < 240) {
    const int rc = tid >> 2;
    const int p = tid & 3;
    const int r = rc / 3;
    const int c = rc - r * 3;
    unsigned short* lp = (unsigned short*)&yS[r * YST + c * 256];

    float sum = 0.f, sq = 0.f;
#pragma unroll
    for (int s = 0; s < 8; ++s) {
      u16x8 v = *(const u16x8*)&lp[(s * 4 + p) * 8];
#pragma unroll
      for (int e = 0; e < 8; ++e) {
        float t = bf2f(v[e]);
        sum += t;
        sq += t * t;
      }
    }
    sum += __shfl_xor(sum, 1, 64); sq += __shfl_xor(sq, 1, 64);
    sum += __shfl_xor(sum, 2, 64); sq += __shfl_xor(sq, 2, 64);

    const float mean = sum * (1.0f / 256.0f);
    const float var = sq * (1.0f / 256.0f) - mean * mean;
    const float rstd = rsqrtf(var + 1e-5f);
    const float osc = (c == 0) ? QSCALE : 1.0f;

    const float* g = (c == 0) ? gq : (c == 1) ? gk : gv;
    const float* bb = (c == 0) ? bq : (c == 1) ? bk : bv;

#pragma unroll
    for (int s = 0; s < 8; ++s) {
      const int c0 = (s * 4 + p) * 8;
      u16x8 v = *(const u16x8*)&lp[c0];
      u16x8 xv = xr[s];
      float4 g0 = *(const float4*)&g[c0];
      float4 g1 = *(const float4*)&g[c0 + 4];
      float4 b0 = *(const float4*)&bb[c0];
      float4 b1 = *(const float4*)&bb[c0 + 4];
      const float* gf0 = (const float*)&g0;
      const float* gf1 = (const float*)&g1;
      const float* bf0 = (const float*)&b0;
      const float* bf1 = (const float*)&b1;
      __align__(16) __hip_bfloat16 h[8];
#pragma unroll
      for (int e = 0; e < 4; ++e)
        h[e] = __float2bfloat16(
            (bf2f(xv[e]) + (bf2f(v[e]) - mean) * rstd * gf0[e] + bf0[e]) * osc);
#pragma unroll
      for (int e = 0; e < 4; ++e)
        h[4 + e] = __float2bfloat16(
            (bf2f(xv[4 + e]) + (bf2f(v[4 + e]) - mean) * rstd * gf1[e] + bf1[e]) * osc);
      *(int4*)&lp[c0] = *(const int4*)h;
    }
  }
  __syncthreads();

  // ---- phase 3: per-wave, 2 heads, no barriers ----
  const unsigned short* ySu = (const unsigned short*)yS;
#pragma unroll
  for (int hh = 0; hh < 2; ++hh) {
    const int h = wave * 2 + hh;
    const int rlo = l16;
    const int rhi = (l16 + 16 < 20) ? (l16 + 16) : 19;  // clamped row

    bf16x8 kf0 = *(const bf16x8*)&yS[rlo * YST + 256 + h * 32 + quad * 8];
    bf16x8 kf1 = *(const bf16x8*)&yS[rhi * YST + 256 + h * 32 + quad * 8];
    bf16x8 qf0 = *(const bf16x8*)&yS[rlo * YST + h * 32 + quad * 8];
    bf16x8 qf1 = *(const bf16x8*)&yS[rhi * YST + h * 32 + quad * 8];

    f32x4 c00, c01, c10, c11;
    {
      const float4 g00 = *(const float4*)&gbias[h * 400 + rlo * 20 + quad * 4];
      const float4 g01 = *(const float4*)&gbias[h * 400 + rhi * 20 + quad * 4];
#pragma unroll
      for (int r = 0; r < 4; ++r) {
        const int j0 = quad * 4 + r;
        const int j1 = (16 + j0 < 20) ? (16 + j0) : 19;
        c00[r] = alpha * ((const float*)&g00)[r] + rel[(rlo - j0 + 19) * 8 + h];
        c01[r] = alpha * ((const float*)&g01)[r] + rel[(rhi - j0 + 19) * 8 + h];
        c10[r] = alpha * gbias[h * 400 + rlo * 20 + j1] + rel[(rlo - j1 + 19) * 8 + h];
        c11[r] = alpha * gbias[h * 400 + rhi * 20 + j1] + rel[(rhi - j1 + 19) * 8 + h];
      }
    }
    c00 = __builtin_amdgcn_mfma_f32_16x16x32_bf16(kf0, qf0, c00, 0, 0, 0);
    c01 = __builtin_amdgcn_mfma_f32_16x16x32_bf16(kf0, qf1, c01, 0, 0, 0);
    c10 = __builtin_amdgcn_mfma_f32_16x16x32_bf16(kf1, qf0, c10, 0, 0, 0);
    c11 = __builtin_amdgcn_mfma_f32_16x16x32_bf16(kf1, qf1, c11, 0, 0, 0);

    float p00[4], p10[4], p01[4], p11[4];
    {
      float m = fmaxf(fmaxf(c00[0], c00[1]), fmaxf(c00[2], c00[3]));
      if (quad == 0)
        m = fmaxf(m, fmaxf(fmaxf(c10[0], c10[1]), fmaxf(c10[2], c10[3])));
      m = fmaxf(m, __shfl_xor(m, 16, 64));
      m = fmaxf(m, __shfl_xor(m, 32, 64));
      float s = 0.f;
#pragma unroll
      for (int r = 0; r < 4; ++r) { p00[r] = __expf(c00[r] - m); s += p00[r]; }
#pragma unroll
      for (int r = 0; r < 4; ++r) {
        p10[r] = (quad == 0) ? __expf(c10[r] - m) : 0.f;
        s += p10[r];
      }
      s += __shfl_xor(s, 16, 64);
      s += __shfl_xor(s, 32, 64);
      const float inv = 1.0f / s;
#pragma unroll
      for (int r = 0; r < 4; ++r) { p00[r] *= inv; p10[r] *= inv; }
    }
    {
      float m = fmaxf(fmaxf(c01[0], c01[1]), fmaxf(c01[2], c01[3]));
      if (quad == 0)
        m = fmaxf(m, fmaxf(fmaxf(c11[0], c11[1]), fmaxf(c11[2], c11[3])));
      m = fmaxf(m, __shfl_xor(m, 16, 64));
      m = fmaxf(m, __shfl_xor(m, 32, 64));
      float s = 0.f;
#pragma unroll
      for (int r = 0; r < 4; ++r) { p01[r] = __expf(c01[r] - m); s += p01[r]; }
#pragma unroll
      for (int r = 0; r < 4; ++r) {
        p11[r] = (quad == 0) ? __expf(c11[r] - m) : 0.f;
        s += p11[r];
      }
      s += __shfl_xor(s, 16, 64);
      s += __shfl_xor(s, 32, 64);
      const float inv = 1.0f / s;
#pragma unroll
      for (int r = 0; r < 4; ++r) { p01[r] *= inv; p11[r] *= inv; }
    }

    const int srcA = ((quad * 2) & 3) * 16 + l16;
    const int srcB = ((quad * 2 + 1) & 3) * 16 + l16;
    __align__(16) __hip_bfloat16 aLo[8], aHi[8];
#pragma unroll
    for (int r = 0; r < 4; ++r) {
      float xa = __shfl(p00[r], srcA, 64);
      float xc = __shfl(p00[r], srcB, 64);
      float xt = __shfl(p10[r], l16, 64);
      float lo = (quad < 2) ? xa : ((quad == 2) ? xt : 0.f);
      float hi = (quad < 2) ? xc : 0.f;
      aLo[r] = __float2bfloat16(lo);
      aLo[4 + r] = __float2bfloat16(hi);
      float ya = __shfl(p01[r], srcA, 64);
      float yc = __shfl(p01[r], srcB, 64);
      float yt = __shfl(p11[r], l16, 64);
      lo = (quad < 2) ? ya : ((quad == 2) ? yt : 0.f);
      hi = (quad < 2) ? yc : 0.f;
      aHi[r] = __float2bfloat16(lo);
      aHi[4 + r] = __float2bfloat16(hi);
    }

    __align__(16) __hip_bfloat16 bv0[8], bv1[8];
#pragma unroll
    for (int e = 0; e < 8; ++e) {
      int jj = quad * 8 + e;
      int jc = (jj < 20) ? jj : 19;
      const __hip_bfloat16* vp =
          (const __hip_bfloat16*)&ySu[jc * YST + 512 + h * 32];
      bv0[e] = vp[l16];
      bv1[e] = vp[16 + l16];
    }

    f32x4 d00 = __builtin_amdgcn_mfma_f32_16x16x32_bf16(
        *(const bf16x8*)aLo, *(const bf16x8*)bv0, zero, 0, 0, 0);
    f32x4 d01 = __builtin_amdgcn_mfma_f32_16x16x32_bf16(
        *(const bf16x8*)aLo, *(const bf16x8*)bv1, zero, 0, 0, 0);
    f32x4 d10 = __builtin_amdgcn_mfma_f32_16x16x32_bf16(
        *(const bf16x8*)aHi, *(const bf16x8*)bv0, zero, 0, 0, 0);
    f32x4 d11 = __builtin_amdgcn_mfma_f32_16x16x32_bf16(
        *(const bf16x8*)aHi, *(const bf16x8*)bv1, zero, 0, 0, 0);

    __hip_bfloat16* aob = ao + (((size_t)(b * 20)) << 8) + h * 32;
#pragma unroll
    for (int r = 0; r < 4; ++r) {
      const int i0 = quad * 4 + r;
      aob[i0 * 256 + l16] = __float2bfloat16(d00[r]);
      aob[i0 * 256 + 16 + l16] = __float2bfloat16(d01[r]);
      const int i1 = 16 + i0;
      if (i1 < 20) {
        aob[i1 * 256 + l16] = __float2bfloat16(d10[r]);
        aob[i1 * 256 + 16 + l16] = __float2bfloat16(d11[r]);
      }
    }
  }
}

// ---------------------------------------------------------------------------
// K4: output projection GEMM, m97 recipe + XCD-aware swizzle (2560 = 8*160*2):
// each XCD owns 160 m-tiles, iterating both n-tiles locally -> ao fetched once.
// ---------------------------------------------------------------------------
__global__ __launch_bounds__(256) void proj_gemm_kernel(
    const __hip_bfloat16* __restrict__ ao,
    const __hip_bfloat16* __restrict__ wob,
    const float* __restrict__ bo,
    float* __restrict__ out) {
  __shared__ __align__(16) __hip_bfloat16 As[128 * 64];
  __shared__ __align__(16) __hip_bfloat16 Bs[128 * 64];

  const int tid = threadIdx.x;
  const int lane = tid & 63;
  const int wave = tid >> 6;
  const int wm = (wave >> 1) << 6;
  const int wn = (wave & 1) << 6;
  const int l16 = lane & 15;
  const int quad = lane >> 4;

  const int bid = blockIdx.x;
  const int xcd = bid & 7;
  const int q = bid >> 3;          // 0..319
  const int m0 = (xcd * 160 + (q >> 1)) * 128;
  const int n0 = (q & 1) * 128;

  const __hip_bfloat16* a_base[4];
  const __hip_bfloat16* b_base[4];
  int lds_off[4];
#pragma unroll
  for (int it = 0; it < 4; ++it) {
    int flat = ((it * 4 + wave) << 6) + lane;
    int row = flat >> 3;
    int seg = flat & 7;
    int seg_g = seg ^ (row & 7);
    a_base[it] = ao + (((size_t)(m0 + row)) << 8) + seg_g * 8;
    b_base[it] = wob + (((size_t)(n0 + row)) << 8) + seg_g * 8;
    lds_off[it] = (it * 4 + wave) << 9;
  }

  f32x4 acc[4][4];
  const f32x4 zero = {0.f, 0.f, 0.f, 0.f};
#pragma unroll
  for (int i = 0; i < 4; ++i)
#pragma unroll
    for (int j = 0; j < 4; ++j) acc[i][j] = zero;

  for (int kt = 0; kt < 4; ++kt) {
    const int k0 = kt << 6;
#pragma unroll
    for (int it = 0; it < 4; ++it) {
      load_lds16(a_base[it] + k0, &As[lds_off[it]]);
      load_lds16(b_base[it] + k0, &Bs[lds_off[it]]);
    }
    __syncthreads();

#pragma unroll
    for (int kk = 0; kk < 64; kk += 32) {
      const int sx = (((kk >> 3) + quad) ^ (l16 & 7)) << 3;
      bf16x8 af[4], bfr[4];
#pragma unroll
      for (int i = 0; i < 4; ++i)
        af[i] = *(const bf16x8*)&As[((wm + i * 16 + l16) << 6) + sx];
#pragma unroll
      for (int j = 0; j < 4; ++j)
        bfr[j] = *(const bf16x8*)&Bs[((wn + j * 16 + l16) << 6) + sx];
#pragma unroll
      for (int i = 0; i < 4; ++i)
#pragma unroll
        for (int j = 0; j < 4; ++j)
          acc[i][j] = __builtin_amdgcn_mfma_f32_16x16x32_bf16(af[i], bfr[j],
                                                              acc[i][j], 0, 0, 0);
    }
    __syncthreads();
  }

#pragma unroll
  for (int i = 0; i < 4; ++i)
#pragma unroll
    for (int j = 0; j < 4; ++j) {
      int col = n0 + wn + j * 16 + l16;
      float bias = bo[col];
#pragma unroll
      for (int r = 0; r < 4; ++r) {
        int row = m0 + wm + i * 16 + quad * 4 + r;
        out[(size_t)row * 256 + col] = acc[i][j][r] + bias;
      }
    }
}

// ---------------------------------------------------------------------------
// launch
// ---------------------------------------------------------------------------
extern "C" void kernel_launch(void* const* d_in, const int* in_sizes, int n_in,
                              void* d_out, int out_size, void* d_ws, size_t ws_size,
                              hipStream_t stream) {
  const float* x     = (const float*)d_in[0];
  const float* wq    = (const float*)d_in[1];
  const float* wk    = (const float*)d_in[2];
  const float* wv    = (const float*)d_in[3];
  const float* gq    = (const float*)d_in[4];
  const float* bq    = (const float*)d_in[5];
  const float* gk    = (const float*)d_in[6];
  const float* bk    = (const float*)d_in[7];
  const float* gv    = (const float*)d_in[8];
  const float* bv    = (const float*)d_in[9];
  const float* rel   = (const float*)d_in[10];
  const float* gbias = (const float*)d_in[11];
  const float* alpha = (const float*)d_in[12];
  const float* wo    = (const float*)d_in[13];
  const float* bo    = (const float*)d_in[14];
  float* out = (float*)d_out;

  // workspace layout (bytes); total 420,741,632
  char* ws = (char*)d_ws;
  __hip_bfloat16* xb  = (__hip_bfloat16*)(ws);                 // 83,886,080
  __hip_bfloat16* y   = (__hip_bfloat16*)(ws + 83886080);      // 251,658,240
  __hip_bfloat16* ao  = (__hip_bfloat16*)(ws + 335544320);     // 83,886,080
  __hip_bfloat16* WcT = (__hip_bfloat16*)(ws + 419430400);     // 1,179,648
  __hip_bfloat16* wob = (__hip_bfloat16*)(ws + 420610048);     // 131,072
  int*            zr  = (int*)(ws + 420741120);                // 512

  prep_kernel<<<8192, 256, 0, stream>>>(x, wq, wk, wv, wo, xb, WcT, wob, zr);
  conv_gemm_kernel<<<7680, 256, 0, stream>>>(xb, WcT, y,
                                             (const __hip_bfloat16*)zr);
  attn5_kernel<<<8192, 256, 0, stream>>>(y, xb, rel, gbias, alpha,
                                         gq, bq, gk, bk, gv, bv, ao);
  proj_gemm_kernel<<<2560, 256, 0, stream>>>(ao, wob, bo, out);
}

// Round 7
// 773.641 us; speedup vs baseline: 1.0609x; 1.0609x over previous
//
#include <hip/hip_runtime.h>
#include <hip/hip_bf16.h>
#include <stdint.h>

#define BATCH 8192
#define NNODE 20
#define MROWS 163840
#define KCONV 768
#define NCONV 768
#define QSCALE 0.17677669529663687f

typedef __bf16 bf16x8 __attribute__((ext_vector_type(8)));
typedef float f32x4 __attribute__((ext_vector_type(4)));
typedef unsigned short u16x8 __attribute__((ext_vector_type(8)));

#define GLOBAL_AS __attribute__((address_space(1)))
#define LDS_AS __attribute__((address_space(3)))

__device__ __forceinline__ void load_lds16(const void* g, void* l) {
  __builtin_amdgcn_global_load_lds((const GLOBAL_AS uint32_t*)g,
                                   (LDS_AS uint32_t*)l, 16, 0, 0);
}

__device__ __forceinline__ float bf2f(unsigned short u) {
  union { unsigned int i; float f; } x;
  x.i = ((unsigned int)u) << 16;
  return x.f;
}

// ---------------------------------------------------------------------------
// K1: prep — cast x to bf16, build WcT, cast wo, zero boundary row.
// ---------------------------------------------------------------------------
__global__ void prep_kernel(const float* __restrict__ x,
                            const float* __restrict__ wq,
                            const float* __restrict__ wk,
                            const float* __restrict__ wv,
                            const float* __restrict__ wo,
                            __hip_bfloat16* __restrict__ xb,
                            __hip_bfloat16* __restrict__ WcT,
                            __hip_bfloat16* __restrict__ wob,
                            int* __restrict__ zrow) {
  const int stride = gridDim.x * blockDim.x;
  const int gid = blockIdx.x * blockDim.x + threadIdx.x;

  if (gid < 128) zrow[gid] = 0;

  const int n8 = (MROWS * 256) / 8;
  for (int i8 = gid; i8 < n8; i8 += stride) {
    const float4* xp = ((const float4*)x) + (size_t)i8 * 2;
    float4 a = xp[0];
    float4 b = xp[1];
    __align__(16) __hip_bfloat16 h[8];
    h[0] = __float2bfloat16(a.x); h[1] = __float2bfloat16(a.y);
    h[2] = __float2bfloat16(a.z); h[3] = __float2bfloat16(a.w);
    h[4] = __float2bfloat16(b.x); h[5] = __float2bfloat16(b.y);
    h[6] = __float2bfloat16(b.z); h[7] = __float2bfloat16(b.w);
    ((int4*)xb)[i8] = *(const int4*)h;
  }

  for (int idx = gid; idx < NCONV * KCONV; idx += stride) {
    int n = idx / KCONV;
    int j = idx - n * KCONV;
    int c = n >> 8, o = n & 255;
    int t = j >> 8, i = j & 255;
    const float* w = (c == 0) ? wq : (c == 1) ? wk : wv;
    WcT[idx] = __float2bfloat16(w[(o * 256 + i) * 3 + t]);
  }

  for (int idx = gid; idx < 256 * 256; idx += stride) {
    wob[idx] = __float2bfloat16(wo[idx]);
  }
}

// ---------------------------------------------------------------------------
// K2: conv GEMM — deep-pipelined edition. 256x128 tile, 8 waves (4M x 2N),
// 3 LDS buffers, counted s_waitcnt vmcnt(6): K-tile kt computed from
// buf[kt%3] while kt+1 is landed and kt+2's loads stay IN FLIGHT across the
// barrier (T3+T4). One barrier per K-tile; setprio around MFMA (T5).
// Same seg^(row&7) swizzle + identical kt/kk/acc order as the verified m97
// kernel -> bitwise-identical y. XCD-banded grid: 3840 = 8 x (80 m x 6 n).
// ---------------------------------------------------------------------------
__global__ __launch_bounds__(512, 2) void conv_gemm_kernel(
    const __hip_bfloat16* __restrict__ xb,
    const __hip_bfloat16* __restrict__ WcT,
    __hip_bfloat16* __restrict__ y,
    const __hip_bfloat16* __restrict__ zrow) {
  __shared__ __align__(16) __hip_bfloat16 As[3][256 * 64];  // 96 KB
  __shared__ __align__(16) __hip_bfloat16 Bs[3][128 * 64];  // 48 KB

  const int tid = threadIdx.x;
  const int lane = tid & 63;
  const int wave = tid >> 6;
  const int wr = (wave >> 1) << 6;   // 4 row-groups of 64
  const int wc = (wave & 1) << 6;    // 2 col-groups of 64
  const int l16 = lane & 15;
  const int quad = lane >> 4;

  const int bid = blockIdx.x;
  const int xcd = bid & 7;
  const int g = xcd * 480 + (bid >> 3);  // 0..3839
  const int mt = g / 6;
  const int nt = g - mt * 6;
  const int m0 = mt * 256;
  const int n0 = nt * 128;

  // A staging: 2048 chunks of 16B, 4 per thread
  const __hip_bfloat16* a_base[4];
  const __hip_bfloat16* z_base[4];
  int a_node[4];
  int a_lds[4];
#pragma unroll
  for (int it = 0; it < 4; ++it) {
    int flat = tid + it * 512;
    int row = flat >> 3;
    int seg = flat & 7;
    int seg_g = seg ^ (row & 7);
    int gr = m0 + row;
    int b = gr / 20;
    a_node[it] = gr - b * 20;
    a_base[it] = xb + (long)(gr - 1) * 256 + seg_g * 8;
    z_base[it] = zrow + seg_g * 8;
    a_lds[it] = flat * 8;
  }
  // B staging: 1024 chunks, 2 per thread
  const __hip_bfloat16* b_base[2];
  int b_lds[2];
#pragma unroll
  for (int it = 0; it < 2; ++it) {
    int flat = tid + it * 512;
    int row = flat >> 3;
    int seg = flat & 7;
    int seg_g = seg ^ (row & 7);
    b_base[it] = WcT + (size_t)(n0 + row) * KCONV + seg_g * 8;
    b_lds[it] = flat * 8;
  }

#define STAGE(KT, BUF)                                                        \
  {                                                                           \
    const int t_ = (KT) >> 2;                                                 \
    const int i0_ = ((KT) & 3) << 6;                                          \
    _Pragma("unroll") for (int it = 0; it < 4; ++it) {                        \
      bool ok = (unsigned)(a_node[it] + t_ - 1) < 20u;                        \
      const __hip_bfloat16* ga =                                              \
          ok ? (a_base[it] + t_ * 256 + i0_) : z_base[it];                    \
      load_lds16(ga, &As[BUF][a_lds[it]]);                                    \
    }                                                                         \
    _Pragma("unroll") for (int it = 0; it < 2; ++it) {                        \
      load_lds16(b_base[it] + (KT) * 64, &Bs[BUF][b_lds[it]]);                \
    }                                                                         \
  }

  f32x4 acc[4][4];
  const f32x4 zero = {0.f, 0.f, 0.f, 0.f};
#pragma unroll
  for (int i = 0; i < 4; ++i)
#pragma unroll
    for (int j = 0; j < 4; ++j) acc[i][j] = zero;

  // prologue: stage kt=0,1; wait kt=0 landed (kt=1's 6 loads in flight)
  STAGE(0, 0);
  STAGE(1, 1);
  asm volatile("s_waitcnt vmcnt(6)" ::: "memory");
  __builtin_amdgcn_s_barrier();
  __builtin_amdgcn_sched_barrier(0);

#pragma unroll
  for (int kt = 0; kt < 12; ++kt) {
    const int bc = kt % 3;
    if (kt < 10) {
      const int bs = (kt + 2) % 3;
      STAGE(kt + 2, bs);
    }
#pragma unroll
    for (int kk = 0; kk < 64; kk += 32) {
      const int sx = (((kk >> 3) + quad) ^ (l16 & 7)) << 3;
      bf16x8 af[4], bfr[4];
#pragma unroll
      for (int i = 0; i < 4; ++i)
        af[i] = *(const bf16x8*)&As[bc][((wr + i * 16 + l16) << 6) + sx];
#pragma unroll
      for (int j = 0; j < 4; ++j)
        bfr[j] = *(const bf16x8*)&Bs[bc][((wc + j * 16 + l16) << 6) + sx];
      __builtin_amdgcn_s_setprio(1);
#pragma unroll
      for (int i = 0; i < 4; ++i)
#pragma unroll
        for (int j = 0; j < 4; ++j)
          acc[i][j] = __builtin_amdgcn_mfma_f32_16x16x32_bf16(af[i], bfr[j],
                                                              acc[i][j], 0, 0, 0);
      __builtin_amdgcn_s_setprio(0);
    }
    if (kt < 10) {
      asm volatile("s_waitcnt vmcnt(6)" ::: "memory");
    } else if (kt == 10) {
      asm volatile("s_waitcnt vmcnt(0)" ::: "memory");
    }
    if (kt < 11) {
      __builtin_amdgcn_s_barrier();
      __builtin_amdgcn_sched_barrier(0);
    }
  }
#undef STAGE

#pragma unroll
  for (int i = 0; i < 4; ++i)
#pragma unroll
    for (int j = 0; j < 4; ++j)
#pragma unroll
      for (int r = 0; r < 4; ++r) {
        int row = m0 + wr + i * 16 + quad * 4 + r;
        int col = n0 + wc + j * 16 + l16;
        y[(size_t)row * NCONV + col] = __float2bfloat16(acc[i][j][r]);
      }
}

// ---------------------------------------------------------------------------
// K3: attention, wave-local edition (unchanged from round 5's win).
// ---------------------------------------------------------------------------
#define YST 776
__global__ __launch_bounds__(256) void attn5_kernel(
    const __hip_bfloat16* __restrict__ y,
    const __hip_bfloat16* __restrict__ xb,
    const float* __restrict__ rel,
    const float* __restrict__ gbias,
    const float* __restrict__ alpha_p,
    const float* __restrict__ gq, const float* __restrict__ bq,
    const float* __restrict__ gk, const float* __restrict__ bk,
    const float* __restrict__ gv, const float* __restrict__ bv,
    __hip_bfloat16* __restrict__ ao) {
  __shared__ __align__(16) __hip_bfloat16 yS[20 * YST];  // 31040 B only

  const int b = blockIdx.x;
  const int tid = threadIdx.x;
  const float alpha = alpha_p[0];
  const int lane = tid & 63;
  const int wave = tid >> 6;
  const int l16 = lane & 15;
  const int quad = lane >> 4;
  const f32x4 zero = {0.f, 0.f, 0.f, 0.f};

  // ---- phase 1: stage yS + prefetch xb residual ----
  const int4* src4 = (const int4*)(y + (size_t)b * NNODE * 768);
#pragma unroll
  for (int p = 0; p < 8; ++p) {
    int idx = tid + p * 256;
    if (idx < 1920) {
      int r = idx / 96;
      int c = idx - r * 96;
      *(int4*)&yS[r * YST + c * 8] = src4[idx];
    }
  }
  u16x8 xr[8];
  if (tid < 240) {
    const int rc = tid >> 2;
    const int p = tid & 3;
    const int r = rc / 3;
    const unsigned short* xp =
        (const unsigned short*)&xb[(((size_t)b * NNODE + r)) << 8];
#pragma unroll
    for (int s = 0; s < 8; ++s) xr[s] = *(const u16x8*)&xp[(s * 4 + p) * 8];
  }
  __syncthreads();

  // ---- phase 2: LN + residual in LDS; Q chunk pre-scaled by 1/sqrt(dk) ----
  if (tid < 240) {
    const int rc = tid >> 2;
    const int p = tid & 3;
    const int r = rc / 3;
    const int c = rc - r * 3;
    unsigned short* lp = (unsigned short*)&yS[r * YST + c * 256];

    float sum = 0.f, sq = 0.f;
#pragma unroll
    for (int s = 0; s < 8; ++s) {
      u16x8 v = *(const u16x8*)&lp[(s * 4 + p) * 8];
#pragma unroll
      for (int e = 0; e < 8; ++e) {
        float t = bf2f(v[e]);
        sum += t;
        sq += t * t;
      }
    }
    sum += __shfl_xor(sum, 1, 64); sq += __shfl_xor(sq, 1, 64);
    sum += __shfl_xor(sum, 2, 64); sq += __shfl_xor(sq, 2, 64);

    const float mean = sum * (1.0f / 256.0f);
    const float var = sq * (1.0f / 256.0f) - mean * mean;
    const float rstd = rsqrtf(var + 1e-5f);
    const float osc = (c == 0) ? QSCALE : 1.0f;

    const float* g = (c == 0) ? gq : (c == 1) ? gk : gv;
    const float* bb = (c == 0) ? bq : (c == 1) ? bk : bv;

#pragma unroll
    for (int s = 0; s < 8; ++s) {
      const int c0 = (s * 4 + p) * 8;
      u16x8 v = *(const u16x8*)&lp[c0];
      u16x8 xv = xr[s];
      float4 g0 = *(const float4*)&g[c0];
      float4 g1 = *(const float4*)&g[c0 + 4];
      float4 b0 = *(const float4*)&bb[c0];
      float4 b1 = *(const float4*)&bb[c0 + 4];
      const float* gf0 = (const float*)&g0;
      const float* gf1 = (const float*)&g1;
      const float* bf0 = (const float*)&b0;
      const float* bf1 = (const float*)&b1;
      __align__(16) __hip_bfloat16 h[8];
#pragma unroll
      for (int e = 0; e < 4; ++e)
        h[e] = __float2bfloat16(
            (bf2f(xv[e]) + (bf2f(v[e]) - mean) * rstd * gf0[e] + bf0[e]) * osc);
#pragma unroll
      for (int e = 0; e < 4; ++e)
        h[4 + e] = __float2bfloat16(
            (bf2f(xv[4 + e]) + (bf2f(v[4 + e]) - mean) * rstd * gf1[e] + bf1[e]) * osc);
      *(int4*)&lp[c0] = *(const int4*)h;
    }
  }
  __syncthreads();

  // ---- phase 3: per-wave, 2 heads, no barriers ----
  const unsigned short* ySu = (const unsigned short*)yS;
#pragma unroll
  for (int hh = 0; hh < 2; ++hh) {
    const int h = wave * 2 + hh;
    const int rlo = l16;
    const int rhi = (l16 + 16 < 20) ? (l16 + 16) : 19;  // clamped row

    bf16x8 kf0 = *(const bf16x8*)&yS[rlo * YST + 256 + h * 32 + quad * 8];
    bf16x8 kf1 = *(const bf16x8*)&yS[rhi * YST + 256 + h * 32 + quad * 8];
    bf16x8 qf0 = *(const bf16x8*)&yS[rlo * YST + h * 32 + quad * 8];
    bf16x8 qf1 = *(const bf16x8*)&yS[rhi * YST + h * 32 + quad * 8];

    f32x4 c00, c01, c10, c11;
    {
      const float4 g00 = *(const float4*)&gbias[h * 400 + rlo * 20 + quad * 4];
      const float4 g01 = *(const float4*)&gbias[h * 400 + rhi * 20 + quad * 4];
#pragma unroll
      for (int r = 0; r < 4; ++r) {
        const int j0 = quad * 4 + r;
        const int j1 = (16 + j0 < 20) ? (16 + j0) : 19;
        c00[r] = alpha * ((const float*)&g00)[r] + rel[(rlo - j0 + 19) * 8 + h];
        c01[r] = alpha * ((const float*)&g01)[r] + rel[(rhi - j0 + 19) * 8 + h];
        c10[r] = alpha * gbias[h * 400 + rlo * 20 + j1] + rel[(rlo - j1 + 19) * 8 + h];
        c11[r] = alpha * gbias[h * 400 + rhi * 20 + j1] + rel[(rhi - j1 + 19) * 8 + h];
      }
    }
    c00 = __builtin_amdgcn_mfma_f32_16x16x32_bf16(kf0, qf0, c00, 0, 0, 0);
    c01 = __builtin_amdgcn_mfma_f32_16x16x32_bf16(kf0, qf1, c01, 0, 0, 0);
    c10 = __builtin_amdgcn_mfma_f32_16x16x32_bf16(kf1, qf0, c10, 0, 0, 0);
    c11 = __builtin_amdgcn_mfma_f32_16x16x32_bf16(kf1, qf1, c11, 0, 0, 0);

    float p00[4], p10[4], p01[4], p11[4];
    {
      float m = fmaxf(fmaxf(c00[0], c00[1]), fmaxf(c00[2], c00[3]));
      if (quad == 0)
        m = fmaxf(m, fmaxf(fmaxf(c10[0], c10[1]), fmaxf(c10[2], c10[3])));
      m = fmaxf(m, __shfl_xor(m, 16, 64));
      m = fmaxf(m, __shfl_xor(m, 32, 64));
      float s = 0.f;
#pragma unroll
      for (int r = 0; r < 4; ++r) { p00[r] = __expf(c00[r] - m); s += p00[r]; }
#pragma unroll
      for (int r = 0; r < 4; ++r) {
        p10[r] = (quad == 0) ? __expf(c10[r] - m) : 0.f;
        s += p10[r];
      }
      s += __shfl_xor(s, 16, 64);
      s += __shfl_xor(s, 32, 64);
      const float inv = 1.0f / s;
#pragma unroll
      for (int r = 0; r < 4; ++r) { p00[r] *= inv; p10[r] *= inv; }
    }
    {
      float m = fmaxf(fmaxf(c01[0], c01[1]), fmaxf(c01[2], c01[3]));
      if (quad == 0)
        m = fmaxf(m, fmaxf(fmaxf(c11[0], c11[1]), fmaxf(c11[2], c11[3])));
      m = fmaxf(m, __shfl_xor(m, 16, 64));
      m = fmaxf(m, __shfl_xor(m, 32, 64));
      float s = 0.f;
#pragma unroll
      for (int r = 0; r < 4; ++r) { p01[r] = __expf(c01[r] - m); s += p01[r]; }
#pragma unroll
      for (int r = 0; r < 4; ++r) {
        p11[r] = (quad == 0) ? __expf(c11[r] - m) : 0.f;
        s += p11[r];
      }
      s += __shfl_xor(s, 16, 64);
      s += __shfl_xor(s, 32, 64);
      const float inv = 1.0f / s;
#pragma unroll
      for (int r = 0; r < 4; ++r) { p01[r] *= inv; p11[r] *= inv; }
    }

    const int srcA = ((quad * 2) & 3) * 16 + l16;
    const int srcB = ((quad * 2 + 1) & 3) * 16 + l16;
    __align__(16) __hip_bfloat16 aLo[8], aHi[8];
#pragma unroll
    for (int r = 0; r < 4; ++r) {
      float xa = __shfl(p00[r], srcA, 64);
      float xc = __shfl(p00[r], srcB, 64);
      float xt = __shfl(p10[r], l16, 64);
      float lo = (quad < 2) ? xa : ((quad == 2) ? xt : 0.f);
      float hi = (quad < 2) ? xc : 0.f;
      aLo[r] = __float2bfloat16(lo);
      aLo[4 + r] = __float2bfloat16(hi);
      float ya = __shfl(p01[r], srcA, 64);
      float yc = __shfl(p01[r], srcB, 64);
      float yt = __shfl(p11[r], l16, 64);
      lo = (quad < 2) ? ya : ((quad == 2) ? yt : 0.f);
      hi = (quad < 2) ? yc : 0.f;
      aHi[r] = __float2bfloat16(lo);
      aHi[4 + r] = __float2bfloat16(hi);
    }

    __align__(16) __hip_bfloat16 bv0[8], bv1[8];
#pragma unroll
    for (int e = 0; e < 8; ++e) {
      int jj = quad * 8 + e;
      int jc = (jj < 20) ? jj : 19;
      const __hip_bfloat16* vp =
          (const __hip_bfloat16*)&ySu[jc * YST + 512 + h * 32];
      bv0[e] = vp[l16];
      bv1[e] = vp[16 + l16];
    }

    f32x4 d00 = __builtin_amdgcn_mfma_f32_16x16x32_bf16(
        *(const bf16x8*)aLo, *(const bf16x8*)bv0, zero, 0, 0, 0);
    f32x4 d01 = __builtin_amdgcn_mfma_f32_16x16x32_bf16(
        *(const bf16x8*)aLo, *(const bf16x8*)bv1, zero, 0, 0, 0);
    f32x4 d10 = __builtin_amdgcn_mfma_f32_16x16x32_bf16(
        *(const bf16x8*)aHi, *(const bf16x8*)bv0, zero, 0, 0, 0);
    f32x4 d11 = __builtin_amdgcn_mfma_f32_16x16x32_bf16(
        *(const bf16x8*)aHi, *(const bf16x8*)bv1, zero, 0, 0, 0);

    __hip_bfloat16* aob = ao + (((size_t)(b * 20)) << 8) + h * 32;
#pragma unroll
    for (int r = 0; r < 4; ++r) {
      const int i0 = quad * 4 + r;
      aob[i0 * 256 + l16] = __float2bfloat16(d00[r]);
      aob[i0 * 256 + 16 + l16] = __float2bfloat16(d01[r]);
      const int i1 = 16 + i0;
      if (i1 < 20) {
        aob[i1 * 256 + l16] = __float2bfloat16(d10[r]);
        aob[i1 * 256 + 16 + l16] = __float2bfloat16(d11[r]);
      }
    }
  }
}

// ---------------------------------------------------------------------------
// K4: output projection GEMM, m97 recipe + XCD-aware swizzle (unchanged).
// ---------------------------------------------------------------------------
__global__ __launch_bounds__(256) void proj_gemm_kernel(
    const __hip_bfloat16* __restrict__ ao,
    const __hip_bfloat16* __restrict__ wob,
    const float* __restrict__ bo,
    float* __restrict__ out) {
  __shared__ __align__(16) __hip_bfloat16 As[128 * 64];
  __shared__ __align__(16) __hip_bfloat16 Bs[128 * 64];

  const int tid = threadIdx.x;
  const int lane = tid & 63;
  const int wave = tid >> 6;
  const int wm = (wave >> 1) << 6;
  const int wn = (wave & 1) << 6;
  const int l16 = lane & 15;
  const int quad = lane >> 4;

  const int bid = blockIdx.x;
  const int xcd = bid & 7;
  const int q = bid >> 3;          // 0..319
  const int m0 = (xcd * 160 + (q >> 1)) * 128;
  const int n0 = (q & 1) * 128;

  const __hip_bfloat16* a_base[4];
  const __hip_bfloat16* b_base[4];
  int lds_off[4];
#pragma unroll
  for (int it = 0; it < 4; ++it) {
    int flat = ((it * 4 + wave) << 6) + lane;
    int row = flat >> 3;
    int seg = flat & 7;
    int seg_g = seg ^ (row & 7);
    a_base[it] = ao + (((size_t)(m0 + row)) << 8) + seg_g * 8;
    b_base[it] = wob + (((size_t)(n0 + row)) << 8) + seg_g * 8;
    lds_off[it] = (it * 4 + wave) << 9;
  }

  f32x4 acc[4][4];
  const f32x4 zero = {0.f, 0.f, 0.f, 0.f};
#pragma unroll
  for (int i = 0; i < 4; ++i)
#pragma unroll
    for (int j = 0; j < 4; ++j) acc[i][j] = zero;

  for (int kt = 0; kt < 4; ++kt) {
    const int k0 = kt << 6;
#pragma unroll
    for (int it = 0; it < 4; ++it) {
      load_lds16(a_base[it] + k0, &As[lds_off[it]]);
      load_lds16(b_base[it] + k0, &Bs[lds_off[it]]);
    }
    __syncthreads();

#pragma unroll
    for (int kk = 0; kk < 64; kk += 32) {
      const int sx = (((kk >> 3) + quad) ^ (l16 & 7)) << 3;
      bf16x8 af[4], bfr[4];
#pragma unroll
      for (int i = 0; i < 4; ++i)
        af[i] = *(const bf16x8*)&As[((wm + i * 16 + l16) << 6) + sx];
#pragma unroll
      for (int j = 0; j < 4; ++j)
        bfr[j] = *(const bf16x8*)&Bs[((wn + j * 16 + l16) << 6) + sx];
#pragma unroll
      for (int i = 0; i < 4; ++i)
#pragma unroll
        for (int j = 0; j < 4; ++j)
          acc[i][j] = __builtin_amdgcn_mfma_f32_16x16x32_bf16(af[i], bfr[j],
                                                              acc[i][j], 0, 0, 0);
    }
    __syncthreads();
  }

#pragma unroll
  for (int i = 0; i < 4; ++i)
#pragma unroll
    for (int j = 0; j < 4; ++j) {
      int col = n0 + wn + j * 16 + l16;
      float bias = bo[col];
#pragma unroll
      for (int r = 0; r < 4; ++r) {
        int row = m0 + wm + i * 16 + quad * 4 + r;
        out[(size_t)row * 256 + col] = acc[i][j][r] + bias;
      }
    }
}

// ---------------------------------------------------------------------------
// launch
// ---------------------------------------------------------------------------
extern "C" void kernel_launch(void* const* d_in, const int* in_sizes, int n_in,
                              void* d_out, int out_size, void* d_ws, size_t ws_size,
                              hipStream_t stream) {
  const float* x     = (const float*)d_in[0];
  const float* wq    = (const float*)d_in[1];
  const float* wk    = (const float*)d_in[2];
  const float* wv    = (const float*)d_in[3];
  const float* gq    = (const float*)d_in[4];
  const float* bq    = (const float*)d_in[5];
  const float* gk    = (const float*)d_in[6];
  const float* bk    = (const float*)d_in[7];
  const float* gv    = (const float*)d_in[8];
  const float* bv    = (const float*)d_in[9];
  const float* rel   = (const float*)d_in[10];
  const float* gbias = (const float*)d_in[11];
  const float* alpha = (const float*)d_in[12];
  const float* wo    = (const float*)d_in[13];
  const float* bo    = (const float*)d_in[14];
  float* out = (float*)d_out;

  // workspace layout (bytes); total 420,741,632
  char* ws = (char*)d_ws;
  __hip_bfloat16* xb  = (__hip_bfloat16*)(ws);                 // 83,886,080
  __hip_bfloat16* y   = (__hip_bfloat16*)(ws + 83886080);      // 251,658,240
  __hip_bfloat16* ao  = (__hip_bfloat16*)(ws + 335544320);     // 83,886,080
  __hip_bfloat16* WcT = (__hip_bfloat16*)(ws + 419430400);     // 1,179,648
  __hip_bfloat16* wob = (__hip_bfloat16*)(ws + 420610048);     // 131,072
  int*            zr  = (int*)(ws + 420741120);                // 512

  prep_kernel<<<8192, 256, 0, stream>>>(x, wq, wk, wv, wo, xb, WcT, wob, zr);
  conv_gemm_kernel<<<3840, 512, 0, stream>>>(xb, WcT, y,
                                             (const __hip_bfloat16*)zr);
  attn5_kernel<<<8192, 256, 0, stream>>>(y, xb, rel, gbias, alpha,
                                         gq, bq, gk, bk, gv, bv, ao);
  proj_gemm_kernel<<<2560, 256, 0, stream>>>(ao, wob, bo, out);
}